// Round 8
// baseline (363.103 us; speedup 1.0000x reference)
//
#include <hip/hip_runtime.h>

#define S_TOTAL 17064
#define NB 16
#define NC 80
#define QPB 4266                                  // location-quads per image
#define NXQ 17                                    // 256-quad chunks per image
#define NCG 10                                    // class groups of 8
#define FOCAL_BLOCKS (NB * NCG * NXQ)             // 2720
#define PB_BLOCKS (NB * NXQ)                      // 272
#define TOTAL_BLOCKS (FOCAL_BLOCKS + PB_BLOCKS)   // 2992

typedef float vfloat4 __attribute__((ext_vector_type(4)));

struct Ptrs {
    const float* cls[5];
    const float* cnt[5];
    const float* reg[5];
    const float* cnt_t;   // [B,S,1]
    const float* reg_t;   // [B,S,4]
    const int*   cls_t;   // [B,S,1]
    float*       ws;      // [0:16) cls, [16:32) cnt, [32:48) reg, [48:64) pos, [64] counter
    float*       out;
};

__device__ __forceinline__ float focal_term(float x, bool o) {
    const float xs = o ? x : -x;            // p_t = sigmoid(xs)
    const float af = o ? 0.25f : 0.75f;
    const float em = __expf(-xs);
    const float pt = 1.0f / (1.0f + em);
    const float q  = em * pt;               // 1 - p_t
    return af * q * q * __logf(1.0f + em);  // -af*(1-pt)^2*log(pt)
}

__device__ __forceinline__ float giou_term(float pl, float pt_, float pr, float pb,
                                           float tl, float tt, float tr, float tb) {
    const float overlap = fmaxf(fminf(pr, tr) + fminf(pl, tl), 0.0f) *
                          fmaxf(fminf(pb, tb) + fminf(pt_, tt), 0.0f);
    const float area1 = (pr + pl) * (pb + pt_);
    const float area2 = (tr + tl) * (tb + tt);
    const float uni = area1 + area2 - overlap;
    const float iou = overlap / uni;
    const float ga = fmaxf(fmaxf(pr, tr) + fmaxf(pl, tl), 0.0f) *
                     fmaxf(fmaxf(pb, tb) + fmaxf(pt_, tt), 0.0f);
    const float giou = iou - (ga - uni) / fmaxf(ga, 1e-10f);
    return 1.0f - giou;
}

__device__ __forceinline__ float bce_term(float x, float t) {
    return fmaxf(x, 0.0f) - x * t + __logf(1.0f + __expf(-fabsf(x)));
}

__global__ __launch_bounds__(256, 8) void fcos_main(Ptrs p) {
    const int bid = blockIdx.x;
    const int tid = threadIdx.x;

    float cls_acc = 0.f, cnt_acc = 0.f, reg_acc = 0.f, pos_acc = 0.f;
    int b;

    if (bid < FOCAL_BLOCKS) {
        const int slab  = bid / NXQ;              // (b, cg): 0..159
        const int chunk = bid - slab * NXQ;       // 0..16
        b = slab / NCG;
        const int cg = slab - b * NCG;            // class group 0..9 (8 classes each)
        const int fq = chunk * 256 + tid;         // quad within image, 0..4351

        int lvl, qbase, hw, off;
        if (fq < 3200)      { lvl = 0; qbase = 0;    hw = 12800; off = 0;     }
        else if (fq < 4000) { lvl = 1; qbase = 3200; hw = 3200;  off = 12800; }
        else if (fq < 4200) { lvl = 2; qbase = 4000; hw = 800;   off = 16000; }
        else if (fq < 4252) { lvl = 3; qbase = 4200; hw = 208;   off = 16800; }
        else                { lvl = 4; qbase = 4252; hw = 56;    off = 17008; }
        const bool active = (fq < QPB);

        const int s0  = active ? ((fq - qbase) << 2) : 0;  // clamp keeps loads in-bounds
        const int gs0 = b * S_TOTAL + off + s0;
        const int c0  = cg * 8;
        const float* cp = p.cls[lvl] + (size_t)((b * NC + c0) * hw + s0);

        // ---- 9 independent loads, pinned BEFORE any compute ----
        vfloat4 v[8];
        #pragma unroll
        for (int j = 0; j < 8; ++j)
            v[j] = *(const vfloat4*)(cp + (size_t)(j * hw));
        const int4 tq = *(const int4*)(p.cls_t + gs0);
        __builtin_amdgcn_sched_barrier(0);        // nothing crosses: loads stay hoisted

        float a0 = 0.f, a1 = 0.f, a2 = 0.f, a3 = 0.f;
        #pragma unroll
        for (int j = 0; j < 8; ++j) {
            const int cp1 = c0 + j + 1;
            a0 += focal_term(v[j].x, tq.x == cp1);
            a1 += focal_term(v[j].y, tq.y == cp1);
            a2 += focal_term(v[j].z, tq.z == cp1);
            a3 += focal_term(v[j].w, tq.w == cp1);
        }
        cls_acc = active ? ((a0 + a1) + (a2 + a3)) : 0.f;
    } else {
        const int pb = bid - FOCAL_BLOCKS;
        b = pb / NXQ;
        const int chunk = pb - b * NXQ;
        const int fq = chunk * 256 + tid;

        int lvl, qbase, hw, off;
        if (fq < 3200)      { lvl = 0; qbase = 0;    hw = 12800; off = 0;     }
        else if (fq < 4000) { lvl = 1; qbase = 3200; hw = 3200;  off = 12800; }
        else if (fq < 4200) { lvl = 2; qbase = 4000; hw = 800;   off = 16000; }
        else if (fq < 4252) { lvl = 3; qbase = 4200; hw = 208;   off = 16800; }
        else                { lvl = 4; qbase = 4252; hw = 56;    off = 17008; }

        if (fq < QPB) {
            const int s0  = (fq - qbase) << 2;
            const int gs0 = b * S_TOTAL + off + s0;
            const float4 xc  = *(const float4*)(p.cnt[lvl] + (size_t)(b * hw + s0));
            const float4 tC  = *(const float4*)(p.cnt_t + gs0);
            const float* rp  = p.reg[lvl] + (size_t)(b * 4 * hw + s0);
            const float4 pl  = *(const float4*)(rp);
            const float4 pt_ = *(const float4*)(rp + (size_t)hw);
            const float4 pr  = *(const float4*)(rp + (size_t)(2 * hw));
            const float4 pb_ = *(const float4*)(rp + (size_t)(3 * hw));
            const float4 t0  = *(const float4*)(p.reg_t + (size_t)(gs0 + 0) * 4);
            const float4 t1  = *(const float4*)(p.reg_t + (size_t)(gs0 + 1) * 4);
            const float4 t2  = *(const float4*)(p.reg_t + (size_t)(gs0 + 2) * 4);
            const float4 t3  = *(const float4*)(p.reg_t + (size_t)(gs0 + 3) * 4);

            const float m0 = (tC.x > -1.0f) ? 1.0f : 0.0f;
            const float m1 = (tC.y > -1.0f) ? 1.0f : 0.0f;
            const float m2 = (tC.z > -1.0f) ? 1.0f : 0.0f;
            const float m3 = (tC.w > -1.0f) ? 1.0f : 0.0f;
            pos_acc = m0 + m1 + m2 + m3;
            cnt_acc = bce_term(xc.x, tC.x) * m0 + bce_term(xc.y, tC.y) * m1 +
                      bce_term(xc.z, tC.z) * m2 + bce_term(xc.w, tC.w) * m3;
            reg_acc = giou_term(pl.x, pt_.x, pr.x, pb_.x, t0.x, t0.y, t0.z, t0.w) * m0 +
                      giou_term(pl.y, pt_.y, pr.y, pb_.y, t1.x, t1.y, t1.z, t1.w) * m1 +
                      giou_term(pl.z, pt_.z, pr.z, pb_.z, t2.x, t2.y, t2.z, t2.w) * m2 +
                      giou_term(pl.w, pt_.w, pr.w, pb_.w, t3.x, t3.y, t3.z, t3.w) * m3;
        }
    }

    // ---- block reduction ----
    #pragma unroll
    for (int d = 32; d; d >>= 1) {
        cls_acc += __shfl_down(cls_acc, d);
        cnt_acc += __shfl_down(cnt_acc, d);
        reg_acc += __shfl_down(reg_acc, d);
        pos_acc += __shfl_down(pos_acc, d);
    }

    __shared__ float red[4][4];
    const int wave = tid >> 6;
    const int lane = tid & 63;
    if (lane == 0) {
        red[0][wave] = cls_acc;
        red[1][wave] = cnt_acc;
        red[2][wave] = reg_acc;
        red[3][wave] = pos_acc;
    }
    __syncthreads();
    if (tid == 0) {
        atomicAdd(&p.ws[b], red[0][0] + red[0][1] + red[0][2] + red[0][3]);
        if (bid >= FOCAL_BLOCKS) {
            atomicAdd(&p.ws[16 + b], red[1][0] + red[1][1] + red[1][2] + red[1][3]);
            atomicAdd(&p.ws[32 + b], red[2][0] + red[2][1] + red[2][2] + red[2][3]);
            atomicAdd(&p.ws[48 + b], red[3][0] + red[3][1] + red[3][2] + red[3][3]);
        }
    }

    // ---- last-block finalize ----
    __shared__ int is_last;
    if (tid == 0) {
        __threadfence();
        const int old = __hip_atomic_fetch_add((int*)(p.ws + 64), 1,
                            __ATOMIC_ACQ_REL, __HIP_MEMORY_SCOPE_AGENT);
        is_last = (old == TOTAL_BLOCKS - 1) ? 1 : 0;
    }
    __syncthreads();
    if (is_last && tid < 64) {
        __threadfence();
        float l0 = 0.f, l1 = 0.f, l2 = 0.f;
        if (tid < NB) {
            const float np = fmaxf(__hip_atomic_load(&p.ws[48 + tid],
                __ATOMIC_RELAXED, __HIP_MEMORY_SCOPE_AGENT), 1.0f);
            l0 = __hip_atomic_load(&p.ws[tid],
                __ATOMIC_RELAXED, __HIP_MEMORY_SCOPE_AGENT) / np;
            l1 = __hip_atomic_load(&p.ws[16 + tid],
                __ATOMIC_RELAXED, __HIP_MEMORY_SCOPE_AGENT) / np;
            l2 = __hip_atomic_load(&p.ws[32 + tid],
                __ATOMIC_RELAXED, __HIP_MEMORY_SCOPE_AGENT) / np;
        }
        #pragma unroll
        for (int d = 32; d; d >>= 1) {
            l0 += __shfl_down(l0, d);
            l1 += __shfl_down(l1, d);
            l2 += __shfl_down(l2, d);
        }
        if (tid == 0) {
            l0 *= (1.0f / NB);
            l1 *= (1.0f / NB);
            l2 *= (1.0f / NB);
            p.out[0] = l0;
            p.out[1] = l1;
            p.out[2] = l2;
            p.out[3] = l0 + l1 + l2;
        }
    }
}

extern "C" void kernel_launch(void* const* d_in, const int* in_sizes, int n_in,
                              void* d_out, int out_size, void* d_ws, size_t ws_size,
                              hipStream_t stream) {
    Ptrs p;
    for (int i = 0; i < 5; ++i) {
        p.cls[i] = (const float*)d_in[3 * i + 0];
        p.cnt[i] = (const float*)d_in[3 * i + 1];
        p.reg[i] = (const float*)d_in[3 * i + 2];
    }
    p.cnt_t = (const float*)d_in[15];
    p.reg_t = (const float*)d_in[16];
    p.cls_t = (const int*)  d_in[17];
    p.ws    = (float*)d_ws;
    p.out   = (float*)d_out;

    (void)hipMemsetAsync(d_ws, 0, 68 * sizeof(float), stream);  // sums + counter

    fcos_main<<<dim3(TOTAL_BLOCKS, 1, 1), 256, 0, stream>>>(p);
}

// Round 9
// 219.462 us; speedup vs baseline: 1.6545x; 1.6545x over previous
//
#include <hip/hip_runtime.h>

#define S_TOTAL 17064
#define NB 16
#define NC 80
#define PB_BLOCKS (NB * 17)            // 272 cnt/reg blocks
#define FPB 36                         // focal blocks per image: 25+7+2+1+1
#define FOCAL_BLOCKS (NB * FPB)        // 576
#define TOTAL_BLOCKS (PB_BLOCKS + FOCAL_BLOCKS)   // 848

typedef float vfloat4 __attribute__((ext_vector_type(4)));
#define AS1 __attribute__((address_space(1)))
#define AS3 __attribute__((address_space(3)))

struct Ptrs {
    const float* cls[5];
    const float* cnt[5];
    const float* reg[5];
    const float* cnt_t;   // [B,S,1]
    const float* reg_t;   // [B,S,4]
    const int*   cls_t;   // [B,S,1]
    float*       ws;      // [0:16) cls, [16:32) cnt, [32:48) reg, [48:64) pos, [64] counter
    float*       out;
};

__device__ __forceinline__ float focal_term(float x, bool o) {
    const float xs = o ? x : -x;            // p_t = sigmoid(xs)
    const float af = o ? 0.25f : 0.75f;
    const float em = __expf(-xs);
    const float pt = 1.0f / (1.0f + em);
    const float q  = em * pt;               // 1 - p_t
    return af * q * q * __logf(1.0f + em);  // -af*(1-pt)^2*log(pt)
}

__device__ __forceinline__ float giou_term(float pl, float pt_, float pr, float pb,
                                           float tl, float tt, float tr, float tb) {
    const float overlap = fmaxf(fminf(pr, tr) + fminf(pl, tl), 0.0f) *
                          fmaxf(fminf(pb, tb) + fminf(pt_, tt), 0.0f);
    const float area1 = (pr + pl) * (pb + pt_);
    const float area2 = (tr + tl) * (tb + tt);
    const float uni = area1 + area2 - overlap;
    const float iou = overlap / uni;
    const float ga = fmaxf(fmaxf(pr, tr) + fmaxf(pl, tl), 0.0f) *
                     fmaxf(fmaxf(pb, tb) + fmaxf(pt_, tt), 0.0f);
    const float giou = iou - (ga - uni) / fmaxf(ga, 1e-10f);
    return 1.0f - giou;
}

__device__ __forceinline__ float bce_term(float x, float t) {
    return fmaxf(x, 0.0f) - x * t + __logf(1.0f + __expf(-fabsf(x)));
}

__global__ __launch_bounds__(256) void fcos_main(Ptrs p) {
    const int bid = blockIdx.x;
    const int tid = threadIdx.x;

    __shared__ float sbuf[2][4096];   // 2 x 16 KB: 8 class-rows x 128 quads x 16 B

    float cls_acc = 0.f, cnt_acc = 0.f, reg_acc = 0.f, pos_acc = 0.f;
    int b;

    if (bid >= PB_BLOCKS) {
        // ================= focal: DMA-staged (class x quad) tile =================
        const int fb = bid - PB_BLOCKS;
        b = fb / FPB;
        const int r = fb - b * FPB;

        int lvl, Q0, nqq, off, hw;
        if (r < 25)      { lvl = 0; Q0 = r * 128;        nqq = 3200; off = 0;     hw = 12800; }
        else if (r < 32) { lvl = 1; Q0 = (r - 25) * 128; nqq = 800;  off = 12800; hw = 3200;  }
        else if (r < 34) { lvl = 2; Q0 = (r - 32) * 128; nqq = 200;  off = 16000; hw = 800;   }
        else if (r < 35) { lvl = 3; Q0 = 0;              nqq = 52;   off = 16800; hw = 208;   }
        else             { lvl = 4; Q0 = 0;              nqq = 14;   off = 17008; hw = 56;    }

        const int w = tid >> 6;               // wave 0..3
        const int l = tid & 63;               // lane
        const int h = tid >> 7;               // row half (0/1)
        const int q = tid & 127;              // quad within tile
        const bool valid = (Q0 + q) < nqq;
        const int qc = valid ? (Q0 + q) : (nqq - 1);
        const int4 tq = *(const int4*)(p.cls_t + (b * S_TOTAL + off + 4 * qc));

        const float* clsb = p.cls[lvl];
        // wave w stages segments w*4+i (i<4); row = seg>>1, s = seg&1
        size_t gbase[4];
        int    loff[4];
        #pragma unroll
        for (int i = 0; i < 4; ++i) {
            const int seg = w * 4 + i;
            const int rw  = seg >> 1;
            const int ss  = seg & 1;
            int inrow = Q0 * 4 + ss * 256 + l * 4;
            inrow = (inrow > hw - 4) ? (hw - 4) : inrow;
            gbase[i] = (size_t)(b * NC + rw) * hw + inrow;
            loff[i]  = rw * 512 + ss * 256;   // float index into a 16 KB buffer
        }
        const size_t cstep = (size_t)8 * hw;  // advance 8 class-rows per chunk

        // stage chunk 0
        #pragma unroll
        for (int i = 0; i < 4; ++i)
            __builtin_amdgcn_global_load_lds(
                (const AS1 float*)(clsb + gbase[i]),
                (AS3 float*)(&sbuf[0][loff[i]]), 16, 0, 0);
        __syncthreads();

        float acc = 0.f;
        int cur = 0;
        for (int c = 0; c < 10; ++c) {
            if (c < 9) {
                const size_t adv = (size_t)(c + 1) * cstep;
                #pragma unroll
                for (int i = 0; i < 4; ++i)
                    __builtin_amdgcn_global_load_lds(
                        (const AS1 float*)(clsb + gbase[i] + adv),
                        (AS3 float*)(&sbuf[cur ^ 1][loff[i]]), 16, 0, 0);
            }
            #pragma unroll
            for (int rr = 0; rr < 4; ++rr) {
                const int rowc = h * 4 + rr;
                const vfloat4 x = *(const vfloat4*)(&sbuf[cur][rowc * 512 + q * 4]);
                const int cp1 = c * 8 + rowc + 1;
                acc += focal_term(x.x, tq.x == cp1);
                acc += focal_term(x.y, tq.y == cp1);
                acc += focal_term(x.z, tq.z == cp1);
                acc += focal_term(x.w, tq.w == cp1);
            }
            __syncthreads();                  // drains vmcnt -> chunk c+1 staged
            cur ^= 1;
        }
        cls_acc = valid ? acc : 0.f;
    } else {
        // ================= cnt BCE + GIoU =================
        b = bid / 17;
        const int chunk = bid - b * 17;
        const int fq = chunk * 256 + tid;

        int lvl, qbase, hw, off;
        if (fq < 3200)      { lvl = 0; qbase = 0;    hw = 12800; off = 0;     }
        else if (fq < 4000) { lvl = 1; qbase = 3200; hw = 3200;  off = 12800; }
        else if (fq < 4200) { lvl = 2; qbase = 4000; hw = 800;   off = 16000; }
        else if (fq < 4252) { lvl = 3; qbase = 4200; hw = 208;   off = 16800; }
        else                { lvl = 4; qbase = 4252; hw = 56;    off = 17008; }

        if (fq < 4266) {
            const int s0  = (fq - qbase) << 2;
            const int gs0 = b * S_TOTAL + off + s0;
            const float4 xc  = *(const float4*)(p.cnt[lvl] + (size_t)(b * hw + s0));
            const float4 tC  = *(const float4*)(p.cnt_t + gs0);
            const float* rp  = p.reg[lvl] + (size_t)(b * 4 * hw + s0);
            const float4 pl  = *(const float4*)(rp);
            const float4 pt_ = *(const float4*)(rp + (size_t)hw);
            const float4 pr  = *(const float4*)(rp + (size_t)(2 * hw));
            const float4 pb_ = *(const float4*)(rp + (size_t)(3 * hw));
            const float4 t0  = *(const float4*)(p.reg_t + (size_t)(gs0 + 0) * 4);
            const float4 t1  = *(const float4*)(p.reg_t + (size_t)(gs0 + 1) * 4);
            const float4 t2  = *(const float4*)(p.reg_t + (size_t)(gs0 + 2) * 4);
            const float4 t3  = *(const float4*)(p.reg_t + (size_t)(gs0 + 3) * 4);

            const float m0 = (tC.x > -1.0f) ? 1.0f : 0.0f;
            const float m1 = (tC.y > -1.0f) ? 1.0f : 0.0f;
            const float m2 = (tC.z > -1.0f) ? 1.0f : 0.0f;
            const float m3 = (tC.w > -1.0f) ? 1.0f : 0.0f;
            pos_acc = m0 + m1 + m2 + m3;
            cnt_acc = bce_term(xc.x, tC.x) * m0 + bce_term(xc.y, tC.y) * m1 +
                      bce_term(xc.z, tC.z) * m2 + bce_term(xc.w, tC.w) * m3;
            reg_acc = giou_term(pl.x, pt_.x, pr.x, pb_.x, t0.x, t0.y, t0.z, t0.w) * m0 +
                      giou_term(pl.y, pt_.y, pr.y, pb_.y, t1.x, t1.y, t1.z, t1.w) * m1 +
                      giou_term(pl.z, pt_.z, pr.z, pb_.z, t2.x, t2.y, t2.z, t2.w) * m2 +
                      giou_term(pl.w, pt_.w, pr.w, pb_.w, t3.x, t3.y, t3.z, t3.w) * m3;
        }
    }

    // ---- block reduction ----
    #pragma unroll
    for (int d = 32; d; d >>= 1) {
        cls_acc += __shfl_down(cls_acc, d);
        cnt_acc += __shfl_down(cnt_acc, d);
        reg_acc += __shfl_down(reg_acc, d);
        pos_acc += __shfl_down(pos_acc, d);
    }

    __shared__ float red[4][4];
    const int wv = tid >> 6;
    const int ln = tid & 63;
    if (ln == 0) {
        red[0][wv] = cls_acc;
        red[1][wv] = cnt_acc;
        red[2][wv] = reg_acc;
        red[3][wv] = pos_acc;
    }
    __syncthreads();
    if (tid == 0) {
        atomicAdd(&p.ws[b], red[0][0] + red[0][1] + red[0][2] + red[0][3]);
        if (bid < PB_BLOCKS) {
            atomicAdd(&p.ws[16 + b], red[1][0] + red[1][1] + red[1][2] + red[1][3]);
            atomicAdd(&p.ws[32 + b], red[2][0] + red[2][1] + red[2][2] + red[2][3]);
            atomicAdd(&p.ws[48 + b], red[3][0] + red[3][1] + red[3][2] + red[3][3]);
        }
    }

    // ---- last-block finalize ----
    __shared__ int is_last;
    if (tid == 0) {
        __threadfence();
        const int old = __hip_atomic_fetch_add((int*)(p.ws + 64), 1,
                            __ATOMIC_ACQ_REL, __HIP_MEMORY_SCOPE_AGENT);
        is_last = (old == TOTAL_BLOCKS - 1) ? 1 : 0;
    }
    __syncthreads();
    if (is_last && tid < 64) {
        __threadfence();
        float l0 = 0.f, l1 = 0.f, l2 = 0.f;
        if (tid < NB) {
            const float np = fmaxf(__hip_atomic_load(&p.ws[48 + tid],
                __ATOMIC_RELAXED, __HIP_MEMORY_SCOPE_AGENT), 1.0f);
            l0 = __hip_atomic_load(&p.ws[tid],
                __ATOMIC_RELAXED, __HIP_MEMORY_SCOPE_AGENT) / np;
            l1 = __hip_atomic_load(&p.ws[16 + tid],
                __ATOMIC_RELAXED, __HIP_MEMORY_SCOPE_AGENT) / np;
            l2 = __hip_atomic_load(&p.ws[32 + tid],
                __ATOMIC_RELAXED, __HIP_MEMORY_SCOPE_AGENT) / np;
        }
        #pragma unroll
        for (int d = 32; d; d >>= 1) {
            l0 += __shfl_down(l0, d);
            l1 += __shfl_down(l1, d);
            l2 += __shfl_down(l2, d);
        }
        if (tid == 0) {
            l0 *= (1.0f / NB);
            l1 *= (1.0f / NB);
            l2 *= (1.0f / NB);
            p.out[0] = l0;
            p.out[1] = l1;
            p.out[2] = l2;
            p.out[3] = l0 + l1 + l2;
        }
    }
}

extern "C" void kernel_launch(void* const* d_in, const int* in_sizes, int n_in,
                              void* d_out, int out_size, void* d_ws, size_t ws_size,
                              hipStream_t stream) {
    Ptrs p;
    for (int i = 0; i < 5; ++i) {
        p.cls[i] = (const float*)d_in[3 * i + 0];
        p.cnt[i] = (const float*)d_in[3 * i + 1];
        p.reg[i] = (const float*)d_in[3 * i + 2];
    }
    p.cnt_t = (const float*)d_in[15];
    p.reg_t = (const float*)d_in[16];
    p.cls_t = (const int*)  d_in[17];
    p.ws    = (float*)d_ws;
    p.out   = (float*)d_out;

    (void)hipMemsetAsync(d_ws, 0, 68 * sizeof(float), stream);  // sums + counter

    fcos_main<<<dim3(TOTAL_BLOCKS, 1, 1), 256, 0, stream>>>(p);
}